// Round 6
// baseline (428.271 us; speedup 1.0000x reference)
//
#include <hip/hip_runtime.h>
#include <hip/hip_bf16.h>

typedef __hip_bfloat16 bf16;
typedef short bf16x8 __attribute__((ext_vector_type(8)));
typedef float f32x4 __attribute__((ext_vector_type(4)));

constexpr int Bb = 16, Nn = 1024, Cc = 768, Dd = 384;

static __device__ __forceinline__ f32x4 mfma16(bf16x8 a, bf16x8 b, f32x4 c) {
    return __builtin_amdgcn_mfma_f32_16x16x32_bf16(a, b, c, 0, 0, 0);
}
static __device__ __forceinline__ short f2b(float v) {
    __hip_bfloat16 h = __float2bfloat16(v);
    return *reinterpret_cast<short*>(&h);
}
// async global->LDS DMA, 16B per lane; lds dest = wave-uniform base + lane*16
static __device__ __forceinline__ void ld16(void* lds, const void* g) {
    __builtin_amdgcn_global_load_lds(
        (const __attribute__((address_space(1))) unsigned int*)g,
        (__attribute__((address_space(3))) unsigned int*)lds, 16, 0, 0);
}

// ---- weight transposes: W[k][n] f32 -> WT[n][k] bf16 -------------------------
__global__ __launch_bounds__(256) void transpose_proj(
    const float* __restrict__ W0, const float* __restrict__ W1,
    const float* __restrict__ W2, bf16* __restrict__ out)
{
    __shared__ float t[32][33];
    const float* in = blockIdx.z == 0 ? W0 : blockIdx.z == 1 ? W1 : W2;
    bf16* o = out + (size_t)blockIdx.z * Dd * Cc;
    const int n0 = blockIdx.x * 32, k0 = blockIdx.y * 32;   // n<384, k<768
    const int tx = threadIdx.x & 31, ty = threadIdx.x >> 5;
#pragma unroll
    for (int i = 0; i < 4; i++)
        t[ty + i * 8][tx] = in[(size_t)(k0 + ty + i * 8) * Dd + n0 + tx];
    __syncthreads();
#pragma unroll
    for (int i = 0; i < 4; i++)
        o[(size_t)(n0 + ty + i * 8) * Cc + k0 + tx] = __float2bfloat16(t[tx][ty + i * 8]);
}

__global__ __launch_bounds__(256) void transpose_wout(
    const float* __restrict__ in, bf16* __restrict__ out)
{
    __shared__ float t[32][33];
    const int n0 = blockIdx.x * 32, k0 = blockIdx.y * 32;   // n<768, k<384
    const int tx = threadIdx.x & 31, ty = threadIdx.x >> 5;
#pragma unroll
    for (int i = 0; i < 4; i++)
        t[ty + i * 8][tx] = in[(size_t)(k0 + ty + i * 8) * Cc + n0 + tx];
    __syncthreads();
#pragma unroll
    for (int i = 0; i < 4; i++)
        out[(size_t)(n0 + ty + i * 8) * Dd + k0 + tx] = __float2bfloat16(t[tx][ty + i * 8]);
}

// ---- fused projection GEMM: [16384,768] @ [768,1152] -> theta|phi|gT ---------
// 128x128 tile, BK=32, 4 waves. grid (9 cols, 128 rows): col-inner keeps the
// x row-panel hot in L2 across its 9 column blocks.
__global__ __launch_bounds__(256) void gemm_proj(
    const float* __restrict__ A, const bf16* __restrict__ BT,
    const float* __restrict__ b_t, const float* __restrict__ b_p,
    const float* __restrict__ b_gv,
    bf16* __restrict__ th, bf16* __restrict__ ph, bf16* __restrict__ gt)
{
    __shared__ short As[128 * 40];
    __shared__ short Bs[128 * 40];
    const int tid = threadIdx.x;
    const int lane = tid & 63, w = tid >> 6;
    const int quad = lane >> 4, c = lane & 15;
    const int col0 = blockIdx.x * 128, row0 = blockIdx.y * 128;
    const int wm = (w & 1) * 64, wn = (w >> 1) * 64;

    const f32x4 fz = {0.f, 0.f, 0.f, 0.f};
    f32x4 acc[4][4];
#pragma unroll
    for (int i = 0; i < 4; i++)
#pragma unroll
        for (int j = 0; j < 4; j++) acc[i][j] = fz;

    for (int k0 = 0; k0 < Cc; k0 += 32) {
        __syncthreads();
#pragma unroll
        for (int u = 0; u < 4; u++) {
            const int id = u * 256 + tid;
            const int r = id >> 3, c4 = (id & 7) * 4;
            const float4 v = *reinterpret_cast<const float4*>(A + (size_t)(row0 + r) * Cc + k0 + c4);
            uint2 p;
            p.x = ((unsigned)(unsigned short)f2b(v.y) << 16) | (unsigned short)(unsigned)f2b(v.x);
            p.y = ((unsigned)(unsigned short)f2b(v.w) << 16) | (unsigned short)(unsigned)f2b(v.z);
            *reinterpret_cast<uint2*>(&As[r * 40 + c4]) = p;
        }
#pragma unroll
        for (int u = 0; u < 2; u++) {
            const int id = u * 256 + tid;
            const int r = id >> 2, c8 = (id & 3) * 8;
            const uint4 v = *reinterpret_cast<const uint4*>(BT + (size_t)(col0 + r) * Cc + k0 + c8);
            *reinterpret_cast<uint4*>(&Bs[r * 40 + c8]) = v;
        }
        __syncthreads();

        bf16x8 af[4], bfr[4];
#pragma unroll
        for (int i = 0; i < 4; i++)
            af[i] = *reinterpret_cast<const bf16x8*>(&As[(wm + i * 16 + c) * 40 + quad * 8]);
#pragma unroll
        for (int j = 0; j < 4; j++)
            bfr[j] = *reinterpret_cast<const bf16x8*>(&Bs[(wn + j * 16 + c) * 40 + quad * 8]);
#pragma unroll
        for (int i = 0; i < 4; i++)
#pragma unroll
            for (int j = 0; j < 4; j++)
                acc[i][j] = mfma16(af[i], bfr[j], acc[i][j]);
    }

    const int sel = col0 >= 768 ? 2 : (col0 >= 384 ? 1 : 0);
    const float* bp = sel == 0 ? b_t : sel == 1 ? b_p : b_gv;
    bf16* dst = sel == 0 ? th : sel == 1 ? ph : gt;
    const int cbase = sel * 384;
#pragma unroll
    for (int i = 0; i < 4; i++) {
        const int rowb = row0 + wm + i * 16 + quad * 4;
#pragma unroll
        for (int j = 0; j < 4; j++) {
            const int col = col0 + wn + j * 16 + c;
            const int cl = col - cbase;
            const float bcol = bp[cl];
#pragma unroll
            for (int r = 0; r < 4; r++) {
                const float v = acc[i][j][r] + bcol;
                const int rr = rowb + r;
                if (sel < 2)
                    dst[(size_t)rr * 384 + cl] = __float2bfloat16(v);
                else
                    dst[((size_t)((rr >> 10) * 384 + cl) << 10) + (rr & 1023)] = __float2bfloat16(v);
            }
        }
    }
}

// ---- out-projection GEMM: [16384,384] @ [384,768] + bias + resid -> f32 ------
__global__ __launch_bounds__(256) void gemm_out(
    const bf16* __restrict__ A, const bf16* __restrict__ BT,
    const float* __restrict__ bias, const float* __restrict__ resid,
    float* __restrict__ out)
{
    __shared__ short As[128 * 40];
    __shared__ short Bs[128 * 40];
    const int tid = threadIdx.x;
    const int lane = tid & 63, w = tid >> 6;
    const int quad = lane >> 4, c = lane & 15;
    const int col0 = blockIdx.x * 128, row0 = blockIdx.y * 128;
    const int wm = (w & 1) * 64, wn = (w >> 1) * 64;

    const f32x4 fz = {0.f, 0.f, 0.f, 0.f};
    f32x4 acc[4][4];
#pragma unroll
    for (int i = 0; i < 4; i++)
#pragma unroll
        for (int j = 0; j < 4; j++) acc[i][j] = fz;

    for (int k0 = 0; k0 < Dd; k0 += 32) {
        __syncthreads();
#pragma unroll
        for (int u = 0; u < 2; u++) {
            const int id = u * 256 + tid;
            const int r = id >> 2, c8 = (id & 3) * 8;
            const uint4 v = *reinterpret_cast<const uint4*>(A + (size_t)(row0 + r) * Dd + k0 + c8);
            *reinterpret_cast<uint4*>(&As[r * 40 + c8]) = v;
        }
#pragma unroll
        for (int u = 0; u < 2; u++) {
            const int id = u * 256 + tid;
            const int r = id >> 2, c8 = (id & 3) * 8;
            const uint4 v = *reinterpret_cast<const uint4*>(BT + (size_t)(col0 + r) * Dd + k0 + c8);
            *reinterpret_cast<uint4*>(&Bs[r * 40 + c8]) = v;
        }
        __syncthreads();

        bf16x8 af[4], bfr[4];
#pragma unroll
        for (int i = 0; i < 4; i++)
            af[i] = *reinterpret_cast<const bf16x8*>(&As[(wm + i * 16 + c) * 40 + quad * 8]);
#pragma unroll
        for (int j = 0; j < 4; j++)
            bfr[j] = *reinterpret_cast<const bf16x8*>(&Bs[(wn + j * 16 + c) * 40 + quad * 8]);
#pragma unroll
        for (int i = 0; i < 4; i++)
#pragma unroll
            for (int j = 0; j < 4; j++)
                acc[i][j] = mfma16(af[i], bfr[j], acc[i][j]);
    }

#pragma unroll
    for (int i = 0; i < 4; i++) {
        const int rowb = row0 + wm + i * 16 + quad * 4;
#pragma unroll
        for (int j = 0; j < 4; j++) {
            const int col = col0 + wn + j * 16 + c;
            const float bcol = bias[col];
#pragma unroll
            for (int r = 0; r < 4; r++) {
                const int rr = rowb + r;
                out[(size_t)rr * Cc + col] = acc[i][j][r] + bcol + resid[(size_t)rr * Cc + col];
            }
        }
    }
}

// ---- flash attention v2: DMA-pipelined phi staging, direct-global gT ---------
// grid (16 q-tiles, 16 batches), 4 waves x 16 q-rows. O overwrites theta
// (same layout; each block touches only its own rows, reads before writes).
__global__ __launch_bounds__(256) void flash_attn2(
    bf16* __restrict__ thetaO, const bf16* __restrict__ phi,
    const bf16* __restrict__ gT, const float* __restrict__ adj)
{
    __shared__ char phs[2][24576];     // 32 n-rows x 384 d bf16, 16B-chunk XOR swizzle
    __shared__ short pls[4][16 * 40];  // per-wave P tile

    const int tid = threadIdx.x;
    const int lane = tid & 63, w = tid >> 6;
    const int quad = lane >> 4, c = lane & 15;
    const int qb = blockIdx.x, b = blockIdx.y;

    const bf16* phi_b = phi + (size_t)b * Nn * Dd;
    const bf16* gT_b  = gT + (size_t)b * Dd * Nn;

    // preload theta A-frags (theta region is dead after this -> O may overwrite)
    const size_t thbase = ((size_t)b * Nn + qb * 64 + w * 16 + c) * Dd;
    bf16x8 ath[12];
#pragma unroll
    for (int dq = 0; dq < 12; dq++)
        ath[dq] = *reinterpret_cast<const bf16x8*>(thetaO + thbase + dq * 32 + quad * 8);

    const f32x4 fz = {0.f, 0.f, 0.f, 0.f};
    f32x4 o[24];
#pragma unroll
    for (int t = 0; t < 24; t++) o[t] = fz;
    float mrow[4], lrow[4];
#pragma unroll
    for (int r = 0; r < 4; r++) { mrow[r] = -INFINITY; lrow[r] = 0.f; }

    // prologue: stage chunk 0 (24 wave-ops of 1KB; wave w does 6)
    {
        char* dst = phs[0];
#pragma unroll
        for (int t = 0; t < 6; t++) {
            const int op = w * 6 + t;
            const int gc = op * 64 + lane;
            const int r = gc / 48, j = gc - r * 48;
            ld16(dst + op * 1024, phi_b + (size_t)r * Dd + ((j ^ (r & 7)) << 3));
        }
    }

    for (int ci = 0; ci < 32; ci++) {
        const int n0 = ci * 32;
        __syncthreads();   // compiler drains vmcnt here -> current buffer ready
        const char* buf = phs[ci & 1];

        // adj prefetch (issued before DMA so softmax's vmcnt wait skips the DMA)
        const float* arow = adj + ((size_t)b * Nn + qb * 64 + w * 16 + quad * 4) * Nn + n0;
        float a0[4], a1[4];
#pragma unroll
        for (int r = 0; r < 4; r++) {
            a0[r] = arow[(size_t)r * Nn + c];
            a1[r] = arow[(size_t)r * Nn + 16 + c];
        }

        // QK^T: 16 q x 32 n over D=384 (LDS reads, lgkm only)
        f32x4 s0 = fz, s1 = fz;
#pragma unroll
        for (int dq = 0; dq < 12; dq++) {
            const int sw = ((dq * 4 + quad) ^ (c & 7)) << 4;
            const bf16x8 b0 = *reinterpret_cast<const bf16x8*>(buf + c * 768 + sw);
            const bf16x8 b1 = *reinterpret_cast<const bf16x8*>(buf + (16 + c) * 768 + sw);
            s0 = mfma16(ath[dq], b0, s0);
            s1 = mfma16(ath[dq], b1, s1);
        }

        // issue next-chunk DMA now: streams during softmax + PV
        if (ci < 31) {
            char* dst = phs[(ci + 1) & 1];
#pragma unroll
            for (int t = 0; t < 6; t++) {
                const int op = w * 6 + t;
                const int gc = op * 64 + lane;
                const int r = gc / 48, j = gc - r * 48;
                ld16(dst + op * 1024, phi_b + (size_t)(n0 + 32 + r) * Dd + ((j ^ (r & 7)) << 3));
            }
        }

        // adj multiply + online softmax (C layout: row = quad*4+r, col = c)
        float p0[4], p1[4], alpha[4];
#pragma unroll
        for (int r = 0; r < 4; r++) {
            const float v0 = s0[r] * a0[r];
            const float v1 = s1[r] * a1[r];
            float t = fmaxf(v0, v1);
#pragma unroll
            for (int msk = 1; msk < 16; msk <<= 1) t = fmaxf(t, __shfl_xor(t, msk));
            const float mn = fmaxf(mrow[r], t);
            alpha[r] = __expf(mrow[r] - mn);
            mrow[r] = mn;
            p0[r] = __expf(v0 - mn);
            p1[r] = __expf(v1 - mn);
            float u = p0[r] + p1[r];
#pragma unroll
            for (int msk = 1; msk < 16; msk <<= 1) u += __shfl_xor(u, msk);
            lrow[r] = lrow[r] * alpha[r] + u;
        }
#pragma unroll
        for (int t = 0; t < 24; t++)
#pragma unroll
            for (int r = 0; r < 4; r++) o[t][r] *= alpha[r];

        // P: C layout -> LDS -> A layout (wave-local, no barrier needed)
        short* pl = (short*)pls[w];
#pragma unroll
        for (int r = 0; r < 4; r++) {
            pl[(quad * 4 + r) * 40 + c] = f2b(p0[r]);
            pl[(quad * 4 + r) * 40 + 16 + c] = f2b(p1[r]);
        }
        const bf16x8 ap = *reinterpret_cast<const bf16x8*>(&pl[c * 40 + quad * 8]);

        // PV: B-frags direct from global gT (coalesced 16B/lane)
#pragma unroll
        for (int dn = 0; dn < 24; dn++) {
            const bf16x8 bg = *reinterpret_cast<const bf16x8*>(
                gT_b + (size_t)(dn * 16 + c) * Nn + n0 + quad * 8);
            o[dn] = mfma16(ap, bg, o[dn]);
        }
    }

    float inv[4];
#pragma unroll
    for (int r = 0; r < 4; r++) inv[r] = 1.0f / lrow[r];
    bf16* orow = thetaO + ((size_t)b * Nn + qb * 64 + w * 16 + quad * 4) * Dd;
#pragma unroll
    for (int dn = 0; dn < 24; dn++)
#pragma unroll
        for (int r = 0; r < 4; r++)
            orow[(size_t)r * Dd + dn * 16 + c] = __float2bfloat16(o[dn][r] * inv[r]);
}

// ============================== launcher ======================================
extern "C" void kernel_launch(void* const* d_in, const int* in_sizes, int n_in,
                              void* d_out, int out_size, void* d_ws, size_t ws_size,
                              hipStream_t stream)
{
    const float* x       = (const float*)d_in[0];
    const float* adj     = (const float*)d_in[1];
    const float* W_theta = (const float*)d_in[2];
    const float* b_theta = (const float*)d_in[3];
    const float* W_phi   = (const float*)d_in[4];
    const float* b_phi   = (const float*)d_in[5];
    const float* W_g     = (const float*)d_in[6];
    const float* b_g     = (const float*)d_in[7];
    const float* W_out   = (const float*)d_in[8];
    const float* b_out   = (const float*)d_in[9];
    float* out = (float*)d_out;

    const size_t SZ  = (size_t)Bb * Nn * Dd;   // 6291456
    const size_t WSZ = (size_t)Cc * Dd;        // 294912

    bf16* WT_all = (bf16*)d_ws;                // [1152][768]
    bf16* WoT    = WT_all + 3 * WSZ;           // [768][384]
    bf16* thetaO = WoT + WSZ;                  // [16384][384] theta, then O
    bf16* phi    = thetaO + SZ;                // [16384][384]
    bf16* gT     = phi + SZ;                   // [16][384][1024]
    // total 40.1 MB (< 52.7 MB proven in R5)

    dim3 blk(256);

    transpose_proj<<<dim3(12, 24, 3), blk, 0, stream>>>(W_theta, W_phi, W_g, WT_all);
    transpose_wout<<<dim3(24, 12), blk, 0, stream>>>(W_out, WoT);

    gemm_proj<<<dim3(9, 128), blk, 0, stream>>>(
        x, WT_all, b_theta, b_phi, b_g, thetaO, phi, gT);

    flash_attn2<<<dim3(Nn / 64, Bb), blk, 0, stream>>>(thetaO, phi, gT, adj);

    gemm_out<<<dim3(6, 128), blk, 0, stream>>>(thetaO, WoT, b_out, x, out);
}